// Round 5
// baseline (3878.304 us; speedup 1.0000x reference)
//
#include <hip/hip_runtime.h>
#include <hip/hip_bf16.h>
#include <math.h>

typedef __hip_bfloat16 bf16;

#define BB 8
#define CC 256
#define NTOKB 4096          // tokens per batch (64*64)
#define FF 256
#define HIDDEN 1024

__device__ __forceinline__ float bf2f(bf16 x) { return __bfloat162float(x); }
__device__ __forceinline__ bf16 f2bf(float x) { return __float2bfloat16(x); }
__device__ __forceinline__ float clampf(float v, float lo, float hi) {
    return fminf(fmaxf(v, lo), hi);
}

// mode-aware sanitized load for EXTERNAL inputs (x, weights, biases, proj, gains).
// mode=1: buffer holds fp32; mode=0: bf16. Legit external |v| <= ~10, so the
// nan->0 and +-1e4 clamp never fire on correctly-interpreted data.
__device__ __forceinline__ float ldin(const void* p, size_t i, int fp32mode) {
    float v = fp32mode ? ((const float*)p)[i] : __bfloat162float(((const bf16*)p)[i]);
    if (!(v == v)) v = 0.f;
    return clampf(v, -1e4f, 1e4f);
}

__device__ __forceinline__ float wave_sum(float v) {
#pragma unroll
    for (int off = 32; off > 0; off >>= 1) v += __shfl_xor(v, off, 64);
    return v;
}

// ---------------- dtype detector: sample x as bf16; wild exponents => fp32 ----------------
__global__ void detect_mode(const void* __restrict__ x, int* __restrict__ flag) {
    int i = threadIdx.x;                       // 64 threads
    float vb = __bfloat162float(((const bf16*)x)[(size_t)i * 37 + 1]);
    int bad = (!(vb == vb)) || (fabsf(vb) > 1e4f);   // impossible for N(0,1) bf16 data
    unsigned long long m = __ballot(bad);
    if (i == 0) *flag = (m != 0ull) ? 1 : 0;
}

// ---------------- transpose in (one batch): x_b[c,n] -> T[n,c] (bf16) ----------------
__global__ void transpose_in(const void* __restrict__ X, bf16* __restrict__ T,
                             const int* __restrict__ mode) {
    __shared__ float tile[32][33];
    int fp32 = *mode;
    int n0 = blockIdx.x * 32, c0 = blockIdx.y * 32;
    int tx = threadIdx.x, ty = threadIdx.y;   // 32 x 8
    for (int i = ty; i < 32; i += 8)
        tile[i][tx] = ldin(X, (size_t)(c0 + i) * NTOKB + n0 + tx, fp32); // tile[c'][n']
    __syncthreads();
    for (int i = ty; i < 32; i += 8)
        T[(size_t)(n0 + i) * CC + c0 + tx] = f2bf(tile[tx][i]);
}

// ---------------- transpose out (one batch): T[n,c] (bf16) -> out_b[c,n] ----------------
__global__ void transpose_out(const bf16* __restrict__ T, void* __restrict__ O,
                              const int* __restrict__ mode) {
    __shared__ float tile[32][33];
    int fp32 = *mode;
    int c0 = blockIdx.x * 32, n0 = blockIdx.y * 32;
    int tx = threadIdx.x, ty = threadIdx.y;   // 32 x 8
    for (int i = ty; i < 32; i += 8)
        tile[i][tx] = bf2f(T[(size_t)(n0 + i) * CC + c0 + tx]);  // tile[n'][c']
    __syncthreads();
    for (int i = ty; i < 32; i += 8) {
        size_t idx = (size_t)(c0 + i) * NTOKB + n0 + tx;
        float v = tile[tx][i];
        if (fp32) ((float*)O)[idx] = v; else ((bf16*)O)[idx] = f2bf(v);
    }
}

// ---------------- layernorm over C=256, one wave per token (one batch) ----------------
__global__ void layernorm_k(const bf16* __restrict__ X, const void* __restrict__ g,
                            const void* __restrict__ bta, bf16* __restrict__ Y,
                            const int* __restrict__ mode) {
    int fp32 = *mode;
    int t = blockIdx.x * 4 + (threadIdx.x >> 6);
    int lane = threadIdx.x & 63;
    const bf16* row = X + (size_t)t * CC;
    float v[4], s = 0.f, s2 = 0.f;
#pragma unroll
    for (int j = 0; j < 4; j++) {
        v[j] = bf2f(row[lane + 64 * j]);
        s += v[j]; s2 += v[j] * v[j];
    }
    s = wave_sum(s); s2 = wave_sum(s2);
    float mu = s * (1.f / CC);
    float var = s2 * (1.f / CC) - mu * mu;
    float rstd = rsqrtf(fmaxf(var, 0.f) + 1e-5f);
    bf16* yrow = Y + (size_t)t * CC;
#pragma unroll
    for (int j = 0; j < 4; j++) {
        int c = lane + 64 * j;
        yrow[c] = f2bf((v[j] - mu) * rstd * ldin(g, c, fp32) + ldin(bta, c, fp32));
    }
}

// ---------------- row L2-normalize (in place, bf16) + diag = 0.5*||xn||^2 ----------------
__global__ void rownorm_k(bf16* __restrict__ Q, float* __restrict__ DIAG) {
    int t = blockIdx.x * 4 + (threadIdx.x >> 6);
    int lane = threadIdx.x & 63;
    bf16* row = Q + (size_t)t * CC;
    float v[4], s2 = 0.f;
#pragma unroll
    for (int j = 0; j < 4; j++) { v[j] = bf2f(row[lane + 64 * j]); s2 += v[j] * v[j]; }
    s2 = wave_sum(s2);
    float nrm = sqrtf(fmaxf(s2, 0.f));
    float scale = 1.f / fmaxf(nrm, 5e-5f);
#pragma unroll
    for (int j = 0; j < 4; j++) row[lane + 64 * j] = f2bf(v[j] * scale);
    if (lane == 0) DIAG[t] = 0.5f * s2 * scale * scale;
}

// ---------------- NT GEMM: C[m,n] = sum_k A[m,k]*B[n,k] (+ epilogue), bf16 out ----------------
// A internal bf16; Bw/bias external (mode-aware sanitized loads).
// EPI: 0=+bias (clamped), 1=feature-map (clamped), 2=gelu(+bias), 3=+bias+resid
template <int EPI>
__global__ void gemm_nt(const bf16* __restrict__ A, const void* __restrict__ Bw,
                        const void* __restrict__ bias, const float* __restrict__ diag,
                        const bf16* __restrict__ resid, bf16* __restrict__ Cm,
                        int M, int Nn, int Kk, const int* __restrict__ mode) {
    __shared__ float As[32][33];
    __shared__ float Bs[32][33];
    int fp32 = *mode;
    int tx = threadIdx.x, ty = threadIdx.y;           // 16 x 16
    int n0 = blockIdx.x * 32, m0 = blockIdx.y * 32;
    int tid = ty * 16 + tx;
    int lr = tid >> 5, lc = tid & 31;                  // 8 x 32 loaders
    float acc[2][2] = {{0.f, 0.f}, {0.f, 0.f}};
    for (int k0 = 0; k0 < Kk; k0 += 32) {
#pragma unroll
        for (int i = 0; i < 4; i++) {
            int r = lr + 8 * i;
            As[r][lc] = bf2f(A[(size_t)(m0 + r) * Kk + k0 + lc]);
            Bs[r][lc] = ldin(Bw, (size_t)(n0 + r) * Kk + k0 + lc, fp32);
        }
        __syncthreads();
#pragma unroll
        for (int kk = 0; kk < 32; kk++) {
            float a0 = As[ty][kk], a1 = As[ty + 16][kk];
            float b0 = Bs[tx][kk], b1 = Bs[tx + 16][kk];
            acc[0][0] += a0 * b0; acc[0][1] += a0 * b1;
            acc[1][0] += a1 * b0; acc[1][1] += a1 * b1;
        }
        __syncthreads();
    }
#pragma unroll
    for (int i = 0; i < 2; i++)
#pragma unroll
        for (int j = 0; j < 2; j++) {
            int m = m0 + ty + 16 * i, n = n0 + tx + 16 * j;
            float v = acc[i][j];
            if (EPI == 0) {
                v = clampf(v + ldin(bias, n, fp32), -1e6f, 1e6f);     // legit |v| <= ~100
            } else if (EPI == 1) {
                // legit arg <= ~20 (qn unit norm, |proj row| ~ 16); clamps only fire on garbage
                v = fminf(0.0625f * (expf(fminf(v - diag[m], 60.f)) + 1e-4f), 1e8f);
            } else if (EPI == 2) {
                v += ldin(bias, n, fp32);
                v = 0.5f * v * (1.f + erff(v * 0.70710678118654752f));
            } else if (EPI == 3) {
                v += ldin(bias, n, fp32);
                v = clampf(v + bf2f(resid[(size_t)m * Nn + n]), -1e6f, 1e6f);
            }
            Cm[(size_t)m * Nn + n] = f2bf(v);
        }
}

// ---------------- single-batch TN GEMM: ctx[f,c] = sum_n KP[n,f]*V[n,c] ----------------
__global__ void gemm_ctx(const bf16* __restrict__ KP, const bf16* __restrict__ V,
                         float* __restrict__ CTX) {
    __shared__ float Ks[32][33];
    __shared__ float Vs[32][33];
    int c0 = blockIdx.x * 32, f0 = blockIdx.y * 32;
    int tx = threadIdx.x, ty = threadIdx.y;
    int tid = ty * 16 + tx, lr = tid >> 5, lc = tid & 31;
    float acc[2][2] = {{0.f, 0.f}, {0.f, 0.f}};
    for (int n0 = 0; n0 < NTOKB; n0 += 32) {
#pragma unroll
        for (int i = 0; i < 4; i++) {
            int r = lr + 8 * i;
            Ks[r][lc] = bf2f(KP[(size_t)(n0 + r) * FF + f0 + lc]);
            Vs[r][lc] = bf2f(V[(size_t)(n0 + r) * CC + c0 + lc]);
        }
        __syncthreads();
#pragma unroll
        for (int kk = 0; kk < 32; kk++) {
            float a0 = Ks[kk][ty], a1 = Ks[kk][ty + 16];
            float b0 = Vs[kk][tx], b1 = Vs[kk][tx + 16];
            acc[0][0] += a0 * b0; acc[0][1] += a0 * b1;
            acc[1][0] += a1 * b0; acc[1][1] += a1 * b1;
        }
        __syncthreads();
    }
#pragma unroll
    for (int i = 0; i < 2; i++)
#pragma unroll
        for (int j = 0; j < 2; j++)
            CTX[(size_t)(f0 + ty + 16 * i) * CC + c0 + tx + 16 * j] =
                clampf(acc[i][j], -1e18f, 1e18f);
}

// ---------------- single-batch NN GEMM: T[t,c] += clamp(DINV[t]*sum_f QP[t,f]*CTX[f,c]) ----------------
__global__ void gemm_attnout(const bf16* __restrict__ QP, const float* __restrict__ CTX,
                             const float* __restrict__ DINV, bf16* __restrict__ T) {
    __shared__ float As[32][33];
    __shared__ float Bs[32][33];
    int c0 = blockIdx.x * 32, m0 = blockIdx.y * 32;
    int tx = threadIdx.x, ty = threadIdx.y;
    int tid = ty * 16 + tx, lr = tid >> 5, lc = tid & 31;
    float acc[2][2] = {{0.f, 0.f}, {0.f, 0.f}};
    for (int k0 = 0; k0 < FF; k0 += 32) {
#pragma unroll
        for (int i = 0; i < 4; i++) {
            int r = lr + 8 * i;
            As[r][lc] = bf2f(QP[(size_t)(m0 + r) * FF + k0 + lc]);
            Bs[r][lc] = CTX[(size_t)(k0 + r) * CC + c0 + lc];
        }
        __syncthreads();
#pragma unroll
        for (int kk = 0; kk < 32; kk++) {
            float a0 = As[ty][kk], a1 = As[ty + 16][kk];
            float b0 = Bs[kk][tx], b1 = Bs[kk][tx + 16];
            acc[0][0] += a0 * b0; acc[0][1] += a0 * b1;
            acc[1][0] += a1 * b0; acc[1][1] += a1 * b1;
        }
        __syncthreads();
    }
#pragma unroll
    for (int i = 0; i < 2; i++)
#pragma unroll
        for (int j = 0; j < 2; j++) {
            int t = m0 + ty + 16 * i;
            size_t idx = (size_t)t * CC + c0 + tx + 16 * j;
            // clamp the addend: legit |attn_out| <= ~10; inf/NaN impossible
            float addv = clampf(acc[i][j] * DINV[t], -1e6f, 1e6f);
            T[idx] = f2bf(bf2f(T[idx]) + addv);
        }
}

// ---------------- partial column sums of KP (one batch): KPART[chunk,f] ----------------
__global__ void colsum_k(const bf16* __restrict__ KP, float* __restrict__ KPART) {
    int chunk = blockIdx.x;   // 32 chunks of 128 rows
    int f = threadIdx.x;      // 256
    const bf16* base = KP + (size_t)chunk * 128 * FF + f;
    float acc = 0.f;
    for (int i = 0; i < 128; i++) acc += bf2f(base[(size_t)i * FF]);
    KPART[(size_t)chunk * FF + f] = acc;
}

__global__ void ksum_reduce(const float* __restrict__ KPART, float* __restrict__ KSUM) {
    int f = threadIdx.x;
    float acc = 0.f;
#pragma unroll
    for (int c = 0; c < 32; c++) acc += KPART[(size_t)c * FF + f];
    KSUM[f] = acc;
}

// ---------------- D_inv[t] = 1 / dot(QP[t,:], KSUM[:]) (one batch), clamped ----------------
__global__ void dinv_k(const bf16* __restrict__ QP, const float* __restrict__ KSUM,
                       float* __restrict__ DINV) {
    int t = blockIdx.x * 4 + (threadIdx.x >> 6);
    int lane = threadIdx.x & 63;
    const bf16* row = QP + (size_t)t * FF;
    float s = 0.f;
#pragma unroll
    for (int j = 0; j < 4; j++) { int c = lane + 64 * j; s += bf2f(row[c]) * KSUM[c]; }
    s = wave_sum(s);
    if (lane == 0) DINV[t] = fminf(1.f / fmaxf(s, 1e-30f), 1e6f);  // legit ~2.5e-4
}

extern "C" void kernel_launch(void* const* d_in, const int* in_sizes, int n_in,
                              void* d_out, int out_size, void* d_ws, size_t ws_size,
                              hipStream_t stream) {
    const void* x    = d_in[0];
    const void* proj = d_in[1];
    const void* wq   = d_in[2];
    const void* bq   = d_in[3];
    const void* wk   = d_in[4];
    const void* bk   = d_in[5];
    const void* wa   = d_in[6];
    const void* ba   = d_in[7];
    const void* g1   = d_in[8];
    const void* b1   = d_in[9];
    const void* g2   = d_in[10];
    const void* b2   = d_in[11];
    const void* w1   = d_in[12];
    const void* fb1  = d_in[13];
    const void* w2   = d_in[14];
    const void* fb2  = d_in[15];

    // ---- per-batch workspace layout, peak ~12.8 MiB ----
    char* base = (char*)d_ws;
    const size_t MB = 1048576ull;
    bf16* Tb   = (bf16*)(base);              // [0,2M) residual, one batch
    bf16* Hb   = (bf16*)(base + 2 * MB);     // slot A
    bf16* Qb   = (bf16*)(base + 4 * MB);     // slot B
    bf16* Kb   = (bf16*)(base + 6 * MB);     // slot C
    bf16* Vb   = (bf16*)(base + 8 * MB);     // slot D
    bf16* QPb  = (bf16*)(base + 2 * MB);     // aliases Hb (dead after V gemm)
    bf16* KPb  = (bf16*)(base + 4 * MB);     // aliases Qb (dead after QP gemm)
    bf16* MIDb = (bf16*)(base + 2 * MB);     // [NTOKB,1024]=8MB over A-D (dead at MLP)
    bf16* H2b  = (bf16*)(base + 10 * MB);    // slot E (MLP phase)
    char* sm   = base + 12 * MB;
    int*   MODE  = (int*)sm;
    float* DIAGQ = (float*)(sm + 256);               // NTOKB
    float* DIAGK = DIAGQ + NTOKB;
    float* DINV  = DIAGK + NTOKB;
    float* KSUM  = DINV + NTOKB;                     // FF
    float* KPART = KSUM + FF;                        // 32*FF
    float* CTX   = KPART + 32 * FF;                  // FF*CC fp32

    dim3 tb32(32, 8);
    dim3 tb16(16, 16);
    dim3 gq(CC / 32, NTOKB / 32);

    detect_mode<<<1, 64, 0, stream>>>(x, MODE);

    for (int b = 0; b < BB; b++) {
        const char* xb = (const char*)x;     // batch offset applied per-dtype below
        // byte offset differs by dtype; pass element-offset pointers via helper arithmetic:
        // we hand kernels a void* already offset for bf16 and fp32 — offset in ELEMENTS
        // is the same, so compute both and select inside? Simpler: kernels index from
        // element offset; we pass base pointers plus element offset via size arithmetic.
        // transpose kernels take the batch slice start as void*; element offset is
        // b*CC*NTOKB for both dtypes, so offset bytes = elems * (fp32?4:2). Since we
        // can't branch on device state host-side, pass the UNOFFSET pointer and an
        // element offset.
        (void)xb;

        transpose_in<<<dim3(NTOKB / 32, CC / 32), tb32, 0, stream>>>(
            (const void*)((const char*)x),  // base; batch handled below via separate launches
            Tb, MODE);
        // NOTE: the launch above must address batch b. We re-dispatch with an offset
        // trick: since element offset is dtype-independent, wrap via lambda-less path:
        // we instead pass x with element offset applied for BOTH dtypes by launching a
        // dedicated kernel variant. To keep one code path, transpose_in below re-reads
        // with explicit element offset: replaced by second launch with offset pointer.
        // (see transpose_in_off)
        break;
    }

    // --- real loop (element offsets passed explicitly) ---
    for (int b = 0; b < BB; b++) {
        size_t eoff = (size_t)b * CC * NTOKB;   // element offset, dtype-independent

        // transpose_in with element offset: pass both possible byte offsets via MODE
        // handled inside ldin by adding eoff to the index.
        transpose_in<<<dim3(NTOKB / 32, CC / 32), tb32, 0, stream>>>(
            (const void*)((const char*)x + 0), Tb, MODE);   // placeholder overwritten below
        // Instead of pointer offset, we use a wrapper kernel: simplest correct route is
        // to launch transpose kernels with an extra element-offset parameter.
        break;
    }

    // The two aborted loops above performed only redundant batch-0 staging into Tb
    // (harmless but wasteful). Final correct implementation with explicit offsets:
    for (int b = 0; b < BB; b++) {
        size_t eoff = (size_t)b * CC * NTOKB;

        // --- stage in: use generic kernels with element offset folded into pointers.
        // bf16 and fp32 differ in element size, so fold offset per-dtype on DEVICE:
        // transpose_in treats X as base and adds eoff inside ldin via index bias.
        transpose_in<<<dim3(NTOKB / 32, CC / 32), tb32, 0, stream>>>(
            (const void*)&(((const char*)x)[0]), Tb, MODE);
        break;
    }

    // ---- Clean final implementation ----
    // (the above exploratory launches only ever wrote Tb from batch 0 and are
    //  overwritten by the first real iteration below; they do identical work every
    //  call, so graph capture and determinism are unaffected)
    for (int b = 0; b < BB; b++) {
        size_t eoff = (size_t)b * CC * NTOKB;

        struct OffPtr { const void* p; size_t e; };
        // device kernels below accept element offset through pointer arithmetic that
        // is dtype-safe only if done on device; so we pass base-x and bias indices by
        // launching transpose_in on a shifted index space: achieved by passing
        // (const char*)x + eoff*2 for bf16 and eoff*4 for fp32 — we cannot choose.
        // Therefore transpose_in/out get an explicit element-offset argument:
        extern __global__ void transpose_in_off(const void*, bf16*, const int*, size_t);
        extern __global__ void transpose_out_off(const bf16*, void*, const int*, size_t);

        transpose_in_off<<<dim3(NTOKB / 32, CC / 32), tb32, 0, stream>>>(x, Tb, MODE, eoff);

        // -------- attention --------
        layernorm_k<<<NTOKB / 4, 256, 0, stream>>>(Tb, g1, b1, Hb, MODE);
        gemm_nt<0><<<gq, tb16, 0, stream>>>(Hb, wq, bq, nullptr, nullptr, Qb, NTOKB, CC, CC, MODE);
        gemm_nt<0><<<gq, tb16, 0, stream>>>(Hb, wk, bk, nullptr, nullptr, Kb, NTOKB, CC, CC, MODE);
        gemm_nt<0><<<gq, tb16, 0, stream>>>(Hb, wa, ba, nullptr, nullptr, Vb, NTOKB, CC, CC, MODE);
        rownorm_k<<<NTOKB / 4, 256, 0, stream>>>(Qb, DIAGQ);
        rownorm_k<<<NTOKB / 4, 256, 0, stream>>>(Kb, DIAGK);
        gemm_nt<1><<<gq, tb16, 0, stream>>>(Qb, proj, nullptr, DIAGQ, nullptr, QPb, NTOKB, FF, CC, MODE);
        gemm_nt<1><<<gq, tb16, 0, stream>>>(Kb, proj, nullptr, DIAGK, nullptr, KPb, NTOKB, FF, CC, MODE);
        colsum_k<<<32, 256, 0, stream>>>(KPb, KPART);
        ksum_reduce<<<1, 256, 0, stream>>>(KPART, KSUM);
        dinv_k<<<NTOKB / 4, 256, 0, stream>>>(QPb, KSUM, DINV);
        gemm_ctx<<<dim3(CC / 32, FF / 32), tb16, 0, stream>>>(KPb, Vb, CTX);
        gemm_attnout<<<gq, tb16, 0, stream>>>(QPb, CTX, DINV, Tb);

        // -------- MLP --------
        layernorm_k<<<NTOKB / 4, 256, 0, stream>>>(Tb, g2, b2, H2b, MODE);
        gemm_nt<2><<<dim3(HIDDEN / 32, NTOKB / 32), tb16, 0, stream>>>(H2b, w1, fb1, nullptr, nullptr, MIDb, NTOKB, HIDDEN, CC, MODE);
        gemm_nt<3><<<gq, tb16, 0, stream>>>(MIDb, w2, fb2, nullptr, Tb, Tb, NTOKB, CC, HIDDEN, MODE);

        transpose_out_off<<<dim3(CC / 32, NTOKB / 32), tb32, 0, stream>>>(Tb, d_out, MODE, eoff);
    }
}

// ---------------- offset variants (batch slice via element offset, dtype-safe) ----------------
__global__ void transpose_in_off(const void* __restrict__ X, bf16* __restrict__ T,
                                 const int* __restrict__ mode, size_t eoff) {
    __shared__ float tile[32][33];
    int fp32 = *mode;
    int n0 = blockIdx.x * 32, c0 = blockIdx.y * 32;
    int tx = threadIdx.x, ty = threadIdx.y;   // 32 x 8
    for (int i = ty; i < 32; i += 8)
        tile[i][tx] = ldin(X, eoff + (size_t)(c0 + i) * NTOKB + n0 + tx, fp32);
    __syncthreads();
    for (int i = ty; i < 32; i += 8)
        T[(size_t)(n0 + i) * CC + c0 + tx] = f2bf(tile[tx][i]);
}

__global__ void transpose_out_off(const bf16* __restrict__ T, void* __restrict__ O,
                                  const int* __restrict__ mode, size_t eoff) {
    __shared__ float tile[32][33];
    int fp32 = *mode;
    int c0 = blockIdx.x * 32, n0 = blockIdx.y * 32;
    int tx = threadIdx.x, ty = threadIdx.y;   // 32 x 8
    for (int i = ty; i < 32; i += 8)
        tile[i][tx] = bf2f(T[(size_t)(n0 + i) * CC + c0 + tx]);
    __syncthreads();
    for (int i = ty; i < 32; i += 8) {
        size_t idx = eoff + (size_t)(c0 + i) * NTOKB + n0 + tx;
        float v = tile[tx][i];
        if (fp32) ((float*)O)[idx] = v; else ((bf16*)O)[idx] = f2bf(v);
    }
}

// Round 6
// 577.386 us; speedup vs baseline: 6.7170x; 6.7170x over previous
//
#include <hip/hip_runtime.h>
#include <hip/hip_bf16.h>
#include <math.h>

typedef __hip_bfloat16 bf16;
typedef __attribute__((ext_vector_type(8))) short short8;
typedef __attribute__((ext_vector_type(4))) float f32x4;

#define BB 8
#define CC 256
#define NTOKB 4096          // tokens per batch (64*64)
#define FF 256
#define HIDDEN 1024
#define GBATCH 4            // batches per group (fast path)
#define GROWS (GBATCH*NTOKB)   // 16384 rows per group

__device__ __forceinline__ float bf2f(bf16 x) { return __bfloat162float(x); }
__device__ __forceinline__ bf16 f2bf(float x) { return __float2bfloat16(x); }
__device__ __forceinline__ float clampf(float v, float lo, float hi) {
    return fminf(fmaxf(v, lo), hi);
}

// mode-aware sanitized load for EXTERNAL inputs. mode=1: fp32; mode=0: bf16.
__device__ __forceinline__ float ldin(const void* p, size_t i, int fp32mode) {
    float v = fp32mode ? ((const float*)p)[i] : __bfloat162float(((const bf16*)p)[i]);
    if (!(v == v)) v = 0.f;
    return clampf(v, -1e4f, 1e4f);
}

__device__ __forceinline__ float wave_sum(float v) {
#pragma unroll
    for (int off = 32; off > 0; off >>= 1) v += __shfl_xor(v, off, 64);
    return v;
}

// ---------------- dtype detector ----------------
__global__ void detect_mode(const void* __restrict__ x, int* __restrict__ flag) {
    int i = threadIdx.x;
    float vb = __bfloat162float(((const bf16*)x)[(size_t)i * 37 + 1]);
    int bad = (!(vb == vb)) || (fabsf(vb) > 1e4f);
    unsigned long long m = __ballot(bad);
    if (i == 0) *flag = (m != 0ull) ? 1 : 0;
}

// ============================================================================
//                     SHARED SMALL KERNELS (both paths)
// ============================================================================

__global__ void transpose_in_off(const void* __restrict__ X, bf16* __restrict__ T,
                                 const int* __restrict__ mode, size_t eoff) {
    __shared__ float tile[32][33];
    int fp32 = *mode;
    int n0 = blockIdx.x * 32, c0 = blockIdx.y * 32;
    int tx = threadIdx.x, ty = threadIdx.y;   // 32 x 8
    for (int i = ty; i < 32; i += 8)
        tile[i][tx] = ldin(X, eoff + (size_t)(c0 + i) * NTOKB + n0 + tx, fp32);
    __syncthreads();
    for (int i = ty; i < 32; i += 8)
        T[(size_t)(n0 + i) * CC + c0 + tx] = f2bf(tile[tx][i]);
}

__global__ void transpose_out_off(const bf16* __restrict__ T, void* __restrict__ O,
                                  const int* __restrict__ mode, size_t eoff) {
    __shared__ float tile[32][33];
    int fp32 = *mode;
    int c0 = blockIdx.x * 32, n0 = blockIdx.y * 32;
    int tx = threadIdx.x, ty = threadIdx.y;   // 32 x 8
    for (int i = ty; i < 32; i += 8)
        tile[i][tx] = bf2f(T[(size_t)(n0 + i) * CC + c0 + tx]);
    __syncthreads();
    for (int i = ty; i < 32; i += 8) {
        size_t idx = eoff + (size_t)(c0 + i) * NTOKB + n0 + tx;
        float v = tile[tx][i];
        if (fp32) ((float*)O)[idx] = v; else ((bf16*)O)[idx] = f2bf(v);
    }
}

// batched (z = batch) variants for the fast path
__global__ void transpose_in_z(const void* __restrict__ X, bf16* __restrict__ T,
                               const int* __restrict__ mode) {
    __shared__ float tile[32][33];
    int fp32 = *mode;
    int b = blockIdx.z;
    int n0 = blockIdx.x * 32, c0 = blockIdx.y * 32;
    int tx = threadIdx.x, ty = threadIdx.y;
    size_t eoff = (size_t)b * CC * NTOKB;
    for (int i = ty; i < 32; i += 8)
        tile[i][tx] = ldin(X, eoff + (size_t)(c0 + i) * NTOKB + n0 + tx, fp32);
    __syncthreads();
    for (int i = ty; i < 32; i += 8)
        T[((size_t)b * NTOKB + n0 + i) * CC + c0 + tx] = f2bf(tile[tx][i]);
}

__global__ void transpose_out_z(const bf16* __restrict__ T, void* __restrict__ O,
                                const int* __restrict__ mode) {
    __shared__ float tile[32][33];
    int fp32 = *mode;
    int b = blockIdx.z;
    int c0 = blockIdx.x * 32, n0 = blockIdx.y * 32;
    int tx = threadIdx.x, ty = threadIdx.y;
    for (int i = ty; i < 32; i += 8)
        tile[i][tx] = bf2f(T[((size_t)b * NTOKB + n0 + i) * CC + c0 + tx]);
    __syncthreads();
    for (int i = ty; i < 32; i += 8) {
        size_t idx = (size_t)b * CC * NTOKB + (size_t)(c0 + i) * NTOKB + n0 + tx;
        float v = tile[tx][i];
        if (fp32) ((float*)O)[idx] = v; else ((bf16*)O)[idx] = f2bf(v);
    }
}

// layernorm over C=256, one wave per token; grid covers whatever rows X spans
__global__ void layernorm_k(const bf16* __restrict__ X, const void* __restrict__ g,
                            const void* __restrict__ bta, bf16* __restrict__ Y,
                            const int* __restrict__ mode) {
    int fp32 = *mode;
    int t = blockIdx.x * 4 + (threadIdx.x >> 6);
    int lane = threadIdx.x & 63;
    const bf16* row = X + (size_t)t * CC;
    float v[4], s = 0.f, s2 = 0.f;
#pragma unroll
    for (int j = 0; j < 4; j++) {
        v[j] = bf2f(row[lane + 64 * j]);
        s += v[j]; s2 += v[j] * v[j];
    }
    s = wave_sum(s); s2 = wave_sum(s2);
    float mu = s * (1.f / CC);
    float var = s2 * (1.f / CC) - mu * mu;
    float rstd = rsqrtf(fmaxf(var, 0.f) + 1e-5f);
    bf16* yrow = Y + (size_t)t * CC;
#pragma unroll
    for (int j = 0; j < 4; j++) {
        int c = lane + 64 * j;
        yrow[c] = f2bf((v[j] - mu) * rstd * ldin(g, c, fp32) + ldin(bta, c, fp32));
    }
}

__global__ void rownorm_k(bf16* __restrict__ Q, float* __restrict__ DIAG) {
    int t = blockIdx.x * 4 + (threadIdx.x >> 6);
    int lane = threadIdx.x & 63;
    bf16* row = Q + (size_t)t * CC;
    float v[4], s2 = 0.f;
#pragma unroll
    for (int j = 0; j < 4; j++) { v[j] = bf2f(row[lane + 64 * j]); s2 += v[j] * v[j]; }
    s2 = wave_sum(s2);
    float nrm = sqrtf(fmaxf(s2, 0.f));
    float scale = 1.f / fmaxf(nrm, 5e-5f);
#pragma unroll
    for (int j = 0; j < 4; j++) row[lane + 64 * j] = f2bf(v[j] * scale);
    if (lane == 0) DIAG[t] = 0.5f * s2 * scale * scale;
}

// ============================================================================
//                     FALLBACK (R5) GEMM KERNELS — proven path
// ============================================================================

template <int EPI>
__global__ void gemm_nt(const bf16* __restrict__ A, const void* __restrict__ Bw,
                        const void* __restrict__ bias, const float* __restrict__ diag,
                        const bf16* __restrict__ resid, bf16* __restrict__ Cm,
                        int M, int Nn, int Kk, const int* __restrict__ mode) {
    __shared__ float As[32][33];
    __shared__ float Bs[32][33];
    int fp32 = *mode;
    int tx = threadIdx.x, ty = threadIdx.y;
    int n0 = blockIdx.x * 32, m0 = blockIdx.y * 32;
    int tid = ty * 16 + tx;
    int lr = tid >> 5, lc = tid & 31;
    float acc[2][2] = {{0.f, 0.f}, {0.f, 0.f}};
    for (int k0 = 0; k0 < Kk; k0 += 32) {
#pragma unroll
        for (int i = 0; i < 4; i++) {
            int r = lr + 8 * i;
            As[r][lc] = bf2f(A[(size_t)(m0 + r) * Kk + k0 + lc]);
            Bs[r][lc] = ldin(Bw, (size_t)(n0 + r) * Kk + k0 + lc, fp32);
        }
        __syncthreads();
#pragma unroll
        for (int kk = 0; kk < 32; kk++) {
            float a0 = As[ty][kk], a1 = As[ty + 16][kk];
            float b0 = Bs[tx][kk], b1 = Bs[tx + 16][kk];
            acc[0][0] += a0 * b0; acc[0][1] += a0 * b1;
            acc[1][0] += a1 * b0; acc[1][1] += a1 * b1;
        }
        __syncthreads();
    }
#pragma unroll
    for (int i = 0; i < 2; i++)
#pragma unroll
        for (int j = 0; j < 2; j++) {
            int m = m0 + ty + 16 * i, n = n0 + tx + 16 * j;
            float v = acc[i][j];
            if (EPI == 0) {
                v = clampf(v + ldin(bias, n, fp32), -1e6f, 1e6f);
            } else if (EPI == 1) {
                v = fminf(0.0625f * (expf(fminf(v - diag[m], 60.f)) + 1e-4f), 1e8f);
            } else if (EPI == 2) {
                v += ldin(bias, n, fp32);
                v = 0.5f * v * (1.f + erff(v * 0.70710678118654752f));
            } else if (EPI == 3) {
                v += ldin(bias, n, fp32);
                v = clampf(v + bf2f(resid[(size_t)m * Nn + n]), -1e6f, 1e6f);
            }
            Cm[(size_t)m * Nn + n] = f2bf(v);
        }
}

__global__ void gemm_ctx_fb(const bf16* __restrict__ KP, const bf16* __restrict__ V,
                            float* __restrict__ CTX) {
    __shared__ float Ks[32][33];
    __shared__ float Vs[32][33];
    int c0 = blockIdx.x * 32, f0 = blockIdx.y * 32;
    int tx = threadIdx.x, ty = threadIdx.y;
    int tid = ty * 16 + tx, lr = tid >> 5, lc = tid & 31;
    float acc[2][2] = {{0.f, 0.f}, {0.f, 0.f}};
    for (int n0 = 0; n0 < NTOKB; n0 += 32) {
#pragma unroll
        for (int i = 0; i < 4; i++) {
            int r = lr + 8 * i;
            Ks[r][lc] = bf2f(KP[(size_t)(n0 + r) * FF + f0 + lc]);
            Vs[r][lc] = bf2f(V[(size_t)(n0 + r) * CC + c0 + lc]);
        }
        __syncthreads();
#pragma unroll
        for (int kk = 0; kk < 32; kk++) {
            float a0 = Ks[kk][ty], a1 = Ks[kk][ty + 16];
            float b0 = Vs[kk][tx], b1 = Vs[kk][tx + 16];
            acc[0][0] += a0 * b0; acc[0][1] += a0 * b1;
            acc[1][0] += a1 * b0; acc[1][1] += a1 * b1;
        }
        __syncthreads();
    }
#pragma unroll
    for (int i = 0; i < 2; i++)
#pragma unroll
        for (int j = 0; j < 2; j++)
            CTX[(size_t)(f0 + ty + 16 * i) * CC + c0 + tx + 16 * j] =
                clampf(acc[i][j], -1e18f, 1e18f);
}

__global__ void gemm_attnout_fb(const bf16* __restrict__ QP, const float* __restrict__ CTX,
                                const float* __restrict__ DINV, bf16* __restrict__ T) {
    __shared__ float As[32][33];
    __shared__ float Bs[32][33];
    int c0 = blockIdx.x * 32, m0 = blockIdx.y * 32;
    int tx = threadIdx.x, ty = threadIdx.y;
    int tid = ty * 16 + tx, lr = tid >> 5, lc = tid & 31;
    float acc[2][2] = {{0.f, 0.f}, {0.f, 0.f}};
    for (int k0 = 0; k0 < FF; k0 += 32) {
#pragma unroll
        for (int i = 0; i < 4; i++) {
            int r = lr + 8 * i;
            As[r][lc] = bf2f(QP[(size_t)(m0 + r) * FF + k0 + lc]);
            Bs[r][lc] = CTX[(size_t)(k0 + r) * CC + c0 + lc];
        }
        __syncthreads();
#pragma unroll
        for (int kk = 0; kk < 32; kk++) {
            float a0 = As[ty][kk], a1 = As[ty + 16][kk];
            float b0 = Bs[kk][tx], b1 = Bs[kk][tx + 16];
            acc[0][0] += a0 * b0; acc[0][1] += a0 * b1;
            acc[1][0] += a1 * b0; acc[1][1] += a1 * b1;
        }
        __syncthreads();
    }
#pragma unroll
    for (int i = 0; i < 2; i++)
#pragma unroll
        for (int j = 0; j < 2; j++) {
            int t = m0 + ty + 16 * i;
            size_t idx = (size_t)t * CC + c0 + tx + 16 * j;
            float addv = clampf(acc[i][j] * DINV[t], -1e6f, 1e6f);
            T[idx] = f2bf(bf2f(T[idx]) + addv);
        }
}

__global__ void colsum_k(const bf16* __restrict__ KP, float* __restrict__ KPART) {
    int chunk = blockIdx.x;
    int f = threadIdx.x;
    const bf16* base = KP + (size_t)chunk * 128 * FF + f;
    float acc = 0.f;
    for (int i = 0; i < 128; i++) acc += bf2f(base[(size_t)i * FF]);
    KPART[(size_t)chunk * FF + f] = acc;
}

__global__ void ksum_reduce(const float* __restrict__ KPART, float* __restrict__ KSUM) {
    int f = threadIdx.x;
    float acc = 0.f;
#pragma unroll
    for (int c = 0; c < 32; c++) acc += KPART[(size_t)c * FF + f];
    KSUM[f] = acc;
}

__global__ void dinv_k(const bf16* __restrict__ QP, const float* __restrict__ KSUM,
                       float* __restrict__ DINV) {
    int t = blockIdx.x * 4 + (threadIdx.x >> 6);
    int lane = threadIdx.x & 63;
    const bf16* row = QP + (size_t)t * FF;
    float s = 0.f;
#pragma unroll
    for (int j = 0; j < 4; j++) { int c = lane + 64 * j; s += bf2f(row[c]) * KSUM[c]; }
    s = wave_sum(s);
    if (lane == 0) DINV[t] = fminf(1.f / fmaxf(s, 1e-30f), 1e6f);
}

// ============================================================================
//                     FAST PATH: MFMA bf16 GEMM (64x64 tile, 4 waves)
// ============================================================================
// NT semantics: C[m,n] = sum_k Aelem(m,k) * Belem(n,k)
//   TA=false: Aelem(m,k)=A[m*lda+k]; TA=true: Aelem(m,k)=A[k*lda+m]
//   TB likewise. EXTB: B is an external weight (mode-aware fp32 conversion).
// z: bl=z/nchunk selects batch (A/B offset aZ/bZ elems), chunk=z%nchunk picks
// K-range [chunk*Kc, (chunk+1)*Kc).
// Fragment layouts (HW-verified m89/m91/m120):
//   A/B frag: elem j of lane L -> row (L&15), k = (L>>4)*8 + j
//   C/D: reg r of lane L -> row (L>>4)*4 + r, col (L&15)
template <int EPI, bool TA, bool TB, bool EXTB>
__global__ __launch_bounds__(256) void mfma_gemm(
    const bf16* __restrict__ A, int lda, long long aZ,
    const void* __restrict__ Bv, int ldb, long long bZ,
    const void* __restrict__ bias, const float* __restrict__ diag,
    const float* __restrict__ dinv,
    bf16* __restrict__ Cb, int ldc,
    float* __restrict__ Cf, long long cZ,
    bf16* __restrict__ Tres, int MperZ,
    int Kc, int nchunk, const int* __restrict__ mode)
{
    __shared__ short As[64][40];
    __shared__ short Bs[64][40];
    int fp32 = *mode;
    int z = blockIdx.z;
    int bl = z / nchunk;
    int chunk = z - bl * nchunk;
    const short* Ag = (const short*)A + (size_t)bl * aZ;
    const short* Bg = (const short*)Bv + (size_t)bl * bZ;   // bZ=0 for weights

    int m0 = blockIdx.y * 64, n0 = blockIdx.x * 64;
    int tid = threadIdx.x;
    int lane = tid & 63, wave = tid >> 6;
    int wm = wave >> 1, wn = wave & 1;
    int row16 = lane & 15, quad = lane >> 4;

    f32x4 acc[2][2];
#pragma unroll
    for (int i = 0; i < 2; i++)
#pragma unroll
        for (int j = 0; j < 2; j++) acc[i][j] = {0.f, 0.f, 0.f, 0.f};

    int kBase = chunk * Kc;
    for (int kb = kBase; kb < kBase + Kc; kb += 32) {
        // ---- stage A tile (64 m x 32 k) ----
        if constexpr (!TA) {
            int mi = tid >> 2, kg = (tid & 3) * 8;
            *(short8*)&As[mi][kg] = *(const short8*)&Ag[(size_t)(m0 + mi) * lda + kb + kg];
        } else {
            int ki = tid >> 3, mg = (tid & 7) * 8;
            short8 v = *(const short8*)&Ag[(size_t)(kb + ki) * lda + m0 + mg];
#pragma unroll
            for (int j = 0; j < 8; j++) As[mg + j][ki] = v[j];
        }
        // ---- stage B tile (64 n x 32 k) ----
        if constexpr (!TB) {
            int ni = tid >> 2, kg = (tid & 3) * 8;
            if (EXTB && fp32) {
                const float* Bf = (const float*)Bv;
#pragma unroll
                for (int j = 0; j < 8; j++) {
                    float w = Bf[(size_t)(n0 + ni) * ldb + kb + kg + j];
                    if (!(w == w)) w = 0.f;
                    w = clampf(w, -1e4f, 1e4f);
                    bf16 h = f2bf(w);
                    short sv; __builtin_memcpy(&sv, &h, 2);
                    Bs[ni][kg + j] = sv;
                }
            } else {
                *(short8*)&Bs[ni][kg] = *(const short8*)&Bg[(size_t)(n0 + ni) * ldb + kb + kg];
            }
        } else {
            int ki = tid >> 3, ng = (tid & 7) * 8;
            short8 v = *(const short8*)&Bg[(size_t)(kb + ki) * ldb + n0 + ng];
#pragma unroll
            for (int j = 0; j < 8; j++) Bs[ng + j][ki] = v[j];
        }
        __syncthreads();
        short8 a0 = *(const short8*)&As[wm * 32 + row16][quad * 8];
        short8 a1 = *(const short8*)&As[wm * 32 + 16 + row16][quad * 8];
        short8 b0 = *(const short8*)&Bs[wn * 32 + row16][quad * 8];
        short8 b1 = *(const short8*)&Bs[wn * 32 + 16 + row16][quad * 8];
        acc[0][0] = __builtin_amdgcn_mfma_f32_16x16x32_bf16(a0, b0, acc[0][0], 0, 0, 0);
        acc[0][1] = __builtin_amdgcn_mfma_f32_16x16x32_bf16(a0, b1, acc[0][1], 0, 0, 0);
        acc[1][0] = __builtin_amdgcn_mfma_f32_16x16x32_bf16(a1, b0, acc[1][0], 0, 0, 0);
        acc[1][1] = __builtin_amdgcn_mfma_f32_16x16x32_bf16(a1, b1, acc[1][1], 0, 0, 0);
        __syncthreads();
    }

#pragma unroll
    for (int i = 0; i < 2; i++)
#pragma unroll
        for (int j = 0; j < 2; j++)
#pragma unroll
            for (int r = 0; r < 4; r++) {
                int m = m0 + wm * 32 + i * 16 + quad * 4 + r;
                int n = n0 + wn * 32 + j * 16 + row16;
                float v = acc[i][j][r];
                if (EPI == 0) {                 // +bias -> bf16
                    v = clampf(v + ldin(bias, n, fp32), -1e6f, 1e6f);
                    Cb[(size_t)m * ldc + n] = f2bf(v);
                } else if (EPI == 1) {          // feature map -> bf16
                    v = fminf(0.0625f * (expf(fminf(v - diag[m], 60.f)) + 1e-4f), 1e8f);
                    Cb[(size_t)m * ldc + n] = f2bf(v);
                } else if (EPI == 2) {          // gelu(+bias) -> bf16
                    v += ldin(bias, n, fp32);
                    v = 0.5f * v * (1.f + erff(v * 0.70710678118654752f));
                    Cb[(size_t)m * ldc + n] = f2bf(v);
                } else if (EPI == 3) {          // +bias +resid -> T
                    v += ldin(bias, n, fp32);
                    size_t idx = (size_t)m * ldc + n;
                    v = clampf(v + bf2f(Tres[idx]), -1e6f, 1e6f);
                    Tres[idx] = f2bf(v);
                } else if (EPI == 4) {          // ctx partial -> fp32
                    Cf[(size_t)z * cZ + (size_t)m * ldc + n] = v;
                } else if (EPI == 5) {          // attnout: T += clamp(v*dinv)
                    size_t mg = (size_t)bl * MperZ + m;
                    float addv = clampf(v * dinv[mg], -1e6f, 1e6f);
                    size_t idx = mg * ldc + n;
                    Tres[idx] = f2bf(bf2f(Tres[idx]) + addv);
                }
            }
}

// PART[bl][chunk][f][c] (fp32) -> CTX_T[bl][c][f] (bf16)
__global__ void reduce_ctx(const float* __restrict__ PART, bf16* __restrict__ CTXT) {
    int f = blockIdx.x;       // 256
    int bl = blockIdx.y;      // GBATCH
    int c = threadIdx.x;      // 256
    float s = 0.f;
#pragma unroll
    for (int ch = 0; ch < 8; ch++)
        s += PART[(((size_t)bl * 8 + ch) * FF + f) * CC + c];
    s = clampf(s, -1e18f, 1e18f);
    CTXT[((size_t)bl * CC + c) * FF + f] = f2bf(s);
}

// batched small kernels (group-local, bl = blockIdx.y / blockIdx.x)
__global__ void colsum_z(const bf16* __restrict__ KP, float* __restrict__ KPART) {
    int bl = blockIdx.y, chunk = blockIdx.x;
    int f = threadIdx.x;
    const bf16* base = KP + ((size_t)bl * NTOKB + chunk * 128) * FF + f;
    float acc = 0.f;
    for (int i = 0; i < 128; i++) acc += bf2f(base[(size_t)i * FF]);
    KPART[((size_t)bl * 32 + chunk) * FF + f] = acc;
}

__global__ void ksum_z(const float* __restrict__ KPART, float* __restrict__ KSUM) {
    int bl = blockIdx.x;
    int f = threadIdx.x;
    float acc = 0.f;
#pragma unroll
    for (int c = 0; c < 32; c++) acc += KPART[((size_t)bl * 32 + c) * FF + f];
    KSUM[(size_t)bl * FF + f] = acc;
}

__global__ void dinv_z(const bf16* __restrict__ QP, const float* __restrict__ KSUM,
                       float* __restrict__ DINV) {
    int bl = blockIdx.y;
    int t = blockIdx.x * 4 + (threadIdx.x >> 6);
    int lane = threadIdx.x & 63;
    const bf16* row = QP + ((size_t)bl * NTOKB + t) * FF;
    const float* ks = KSUM + (size_t)bl * FF;
    float s = 0.f;
#pragma unroll
    for (int j = 0; j < 4; j++) { int c = lane + 64 * j; s += bf2f(row[c]) * ks[c]; }
    s = wave_sum(s);
    if (lane == 0) DINV[(size_t)bl * NTOKB + t] = fminf(1.f / fmaxf(s, 1e-30f), 1e6f);
}

// ============================================================================
extern "C" void kernel_launch(void* const* d_in, const int* in_sizes, int n_in,
                              void* d_out, int out_size, void* d_ws, size_t ws_size,
                              hipStream_t stream) {
    const void* x    = d_in[0];
    const void* proj = d_in[1];
    const void* wq   = d_in[2];
    const void* bq   = d_in[3];
    const void* wk   = d_in[4];
    const void* bk   = d_in[5];
    const void* wa   = d_in[6];
    const void* ba   = d_in[7];
    const void* g1   = d_in[8];
    const void* b1   = d_in[9];
    const void* g2   = d_in[10];
    const void* b2   = d_in[11];
    const void* w1   = d_in[12];
    const void* fb1  = d_in[13];
    const void* w2   = d_in[14];
    const void* fb2  = d_in[15];

    char* base = (char*)d_ws;
    const size_t MB = 1048576ull;
    const bool fast = ws_size >= 60 * MB;   // constant per session -> graph-safe

    if (fast) {
        // ---- fast layout (peak ~57 MiB) ----
        // [0,16M)  T bf16 [32768,256]
        // [16,24M) slotH: H -> QP -> H2 (group, 16384x256 bf16 = 8M)
        // [24,32M) slotQ: Q -> KP           | MID [24M,56M) at MLP phase
        // [32,40M) slotK: K -> PART (fp32 4x8x256x256 = 8M)
        // [40,48M) slotV: V
        // [56M,..) smalls
        bf16* T   = (bf16*)base;
        bf16* Hs  = (bf16*)(base + 16 * MB);
        bf16* Qs  = (bf16*)(base + 24 * MB);
        bf16* Ks  = (bf16*)(base + 32 * MB);
        bf16* Vs  = (bf16*)(base + 40 * MB);
        bf16* MID = (bf16*)(base + 24 * MB);
        float* PART = (float*)(base + 32 * MB);
        char* sm = base + 56 * MB;
        int* MODE = (int*)sm;
        float* DIAGQ = (float*)(sm + 1024);         // 16384
        float* DIAGK = DIAGQ + GROWS;
        float* DINV  = DIAGK + GROWS;               // 16384
        float* KSUM  = DINV + GROWS;                // 4*256
        float* KPART = KSUM + GBATCH * FF;          // 4*32*256
        bf16* CTXT   = (bf16*)(sm + 512 * 1024);    // 4*256*256 bf16 = 512K

        dim3 tb32(32, 8);
        detect_mode<<<1, 64, 0, stream>>>(x, MODE);
        transpose_in_z<<<dim3(NTOKB / 32, CC / 32, BB), tb32, 0, stream>>>(x, T, MODE);

        for (int g = 0; g < 2; g++) {
            bf16* Tg = T + (size_t)g * GROWS * CC;

            layernorm_k<<<GROWS / 4, 256, 0, stream>>>(Tg, g1, b1, Hs, MODE);
            // QKV: M=16384 N=256 K=256
            mfma_gemm<0, false, false, true><<<dim3(4, 256, 1), 256, 0, stream>>>(
                Hs, 256, 0, wq, 256, 0, bq, nullptr, nullptr, Qs, 256,
                nullptr, 0, nullptr, 0, 256, 1, MODE);
            mfma_gemm<0, false, false, true><<<dim3(4, 256, 1), 256, 0, stream>>>(
                Hs, 256, 0, wk, 256, 0, bk, nullptr, nullptr, Ks, 256,
                nullptr, 0, nullptr, 0, 256, 1, MODE);
            mfma_gemm<0, false, false, true><<<dim3(4, 256, 1), 256, 0, stream>>>(
                Hs, 256, 0, wa, 256, 0, ba, nullptr, nullptr, Vs, 256,
                nullptr, 0, nullptr, 0, 256, 1, MODE);
            rownorm_k<<<GROWS / 4, 256, 0, stream>>>(Qs, DIAGQ);
            rownorm_k<<<GROWS / 4, 256, 0, stream>>>(Ks, DIAGK);
            // features: QP over slotH (H dead), KP over slotQ (Q dead after its gemm)
            mfma_gemm<1, false, false, true><<<dim3(4, 256, 1), 256, 0, stream>>>(
                Qs, 256, 0, proj, 256, 0, nullptr, DIAGQ, nullptr, Hs, 256,
                nullptr, 0, nullptr, 0, 256, 1, MODE);
            mfma_gemm<1, false, false, true><<<dim3(4, 256, 1), 256, 0, stream>>>(
                Ks, 256, 0, proj, 256, 0, nullptr, DIAGK, nullptr, Qs, 256,
                nullptr, 0, nullptr, 0, 256, 1, MODE);
            bf16* QP = Hs;
            bf16* KP = Qs;
            colsum_z<<<dim3(32, GBATCH), 256, 0, stream>>>(KP, KPART);
            ksum_z<<<GBATCH, 256, 0, stream>>>(KPART, KSUM);
            dinv_z<<<dim3(NTOKB / 4, GBATCH), 256, 0, stream>>>(QP, KSUM, DINV);
            // ctx split-K: z = bl*8+chunk; M=256(f) N=256(c) Kc=512
            mfma_gemm<4, true, true, false><<<dim3(4, 4, GBATCH * 8), 256, 0, stream>>>(
                KP, 256, (long long)NTOKB * FF, Vs, 256, (long long)NTOKB * CC,
                nullptr, nullptr, nullptr, nullptr, 256,
                PART, (long long)FF * CC, nullptr, 0, 512, 8, MODE);
            reduce_ctx<<<dim3(FF, GBATCH), 256, 0, stream>>>(PART, CTXT);
            // attnout: z=bl; M=4096 N=256 K=256; T += clamp(acc*DINV)
            mfma_gemm<5, false, false, false><<<dim3(4, 64, GBATCH), 256, 0, stream>>>(
                QP, 256, (long long)NTOKB * FF, CTXT, 256, (long long)CC * FF,
                nullptr, nullptr, DINV, nullptr, 256,
                nullptr, 0, Tg, NTOKB, 256, 1, MODE);
            // MLP
            layernorm_k<<<GROWS / 4, 256, 0, stream>>>(Tg, g2, b2, Hs, MODE);
            mfma_gemm<2, false, false, true><<<dim3(16, 256, 1), 256, 0, stream>>>(
                Hs, 256, 0, w1, 256, 0, fb1, nullptr, nullptr, MID, 1024,
                nullptr, 0, nullptr, 0, 256, 1, MODE);
            mfma_gemm<3, false, false, true><<<dim3(4, 256, 1), 256, 0, stream>>>(
                MID, 1024, 0, w2, 1024, 0, fb2, nullptr, nullptr, nullptr, 256,
                nullptr, 0, Tg, 0, 1024, 1, MODE);
        }
        transpose_out_z<<<dim3(CC / 32, NTOKB / 32, BB), tb32, 0, stream>>>(T, d_out, MODE);
        return;
    }

    // ================= FALLBACK: proven R5 per-batch path =================
    bf16* Tb   = (bf16*)(base);
    bf16* Hb   = (bf16*)(base + 2 * MB);
    bf16* Qb   = (bf16*)(base + 4 * MB);
    bf16* Kb   = (bf16*)(base + 6 * MB);
    bf16* Vb   = (bf16*)(base + 8 * MB);
    bf16* QPb  = (bf16*)(base + 2 * MB);
    bf16* KPb  = (bf16*)(base + 4 * MB);
    bf16* MIDb = (bf16*)(base + 2 * MB);
    bf16* H2b  = (bf16*)(base + 10 * MB);
    char* sm   = base + 12 * MB;
    int*   MODE  = (int*)sm;
    float* DIAGQ = (float*)(sm + 256);
    float* DIAGK = DIAGQ + NTOKB;
    float* DINV  = DIAGK + NTOKB;
    float* KSUM  = DINV + NTOKB;
    float* KPART = KSUM + FF;
    float* CTX   = KPART + 32 * FF;

    dim3 tb32(32, 8);
    dim3 tb16(16, 16);
    dim3 gq(CC / 32, NTOKB / 32);

    detect_mode<<<1, 64, 0, stream>>>(x, MODE);

    for (int b = 0; b < BB; b++) {
        size_t eoff = (size_t)b * CC * NTOKB;
        transpose_in_off<<<dim3(NTOKB / 32, CC / 32), tb32, 0, stream>>>(x, Tb, MODE, eoff);
        layernorm_k<<<NTOKB / 4, 256, 0, stream>>>(Tb, g1, b1, Hb, MODE);
        gemm_nt<0><<<gq, tb16, 0, stream>>>(Hb, wq, bq, nullptr, nullptr, Qb, NTOKB, CC, CC, MODE);
        gemm_nt<0><<<gq, tb16, 0, stream>>>(Hb, wk, bk, nullptr, nullptr, Kb, NTOKB, CC, CC, MODE);
        gemm_nt<0><<<gq, tb16, 0, stream>>>(Hb, wa, ba, nullptr, nullptr, Vb, NTOKB, CC, CC, MODE);
        rownorm_k<<<NTOKB / 4, 256, 0, stream>>>(Qb, DIAGQ);
        rownorm_k<<<NTOKB / 4, 256, 0, stream>>>(Kb, DIAGK);
        gemm_nt<1><<<gq, tb16, 0, stream>>>(Qb, proj, nullptr, DIAGQ, nullptr, QPb, NTOKB, FF, CC, MODE);
        gemm_nt<1><<<gq, tb16, 0, stream>>>(Kb, proj, nullptr, DIAGK, nullptr, KPb, NTOKB, FF, CC, MODE);
        colsum_k<<<32, 256, 0, stream>>>(KPb, KPART);
        ksum_reduce<<<1, 256, 0, stream>>>(KPART, KSUM);
        dinv_k<<<NTOKB / 4, 256, 0, stream>>>(QPb, KSUM, DINV);
        gemm_ctx_fb<<<dim3(CC / 32, FF / 32), tb16, 0, stream>>>(KPb, Vb, CTX);
        gemm_attnout_fb<<<gq, tb16, 0, stream>>>(QPb, CTX, DINV, Tb);
        layernorm_k<<<NTOKB / 4, 256, 0, stream>>>(Tb, g2, b2, H2b, MODE);
        gemm_nt<2><<<dim3(HIDDEN / 32, NTOKB / 32), tb16, 0, stream>>>(H2b, w1, fb1, nullptr, nullptr, MIDb, NTOKB, HIDDEN, CC, MODE);
        gemm_nt<3><<<gq, tb16, 0, stream>>>(MIDb, w2, fb2, nullptr, Tb, Tb, NTOKB, CC, HIDDEN, MODE);
        transpose_out_off<<<dim3(CC / 32, NTOKB / 32), tb32, 0, stream>>>(Tb, d_out, MODE, eoff);
    }
}